// Round 1
// baseline (14004.643 us; speedup 1.0000x reference)
//
#include <hip/hip_runtime.h>
#include <cstdint>

#define NT    8      // teams (segments)
#define GW    32     // workgroups per team
#define RPW   64     // rows per workgroup (2048 / 32)
#define NTHR  512    // threads per workgroup
#define NRES  2048
#define IDIM  64
#define TTOT  8192
#define SEGL  1024   // TTOT / NT
#define BURN  512    // burn-in steps (echo-state washout); contraction <= 0.955/step
#define RSTR  292    // sparse row stride (not mult of 32 dwords -> avoids LDS bank aliasing)
#define RCAP  288    // max nnz kept per row (mean 205, sigma 13.6 -> 6 sigma safe)
#define WSTR  68     // W_in LDS row stride (floats)

// LDS carve (bytes):
//  s_state : 2048 f            = 8192
//  s_vals  : 64*RSTR f         = 74752
//  s_win   : 64*WSTR f         = 17408
//  s_xt    : 64 f              = 256
//  s_pout  : 64 f              = 256
//  s_pad   : 64 u32            = 256
//  s_idx   : 64*RSTR u16       = 37376
#define LDS_BYTES (8192 + 64*RSTR*4 + 64*WSTR*4 + 256 + 256 + 256 + 64*RSTR*2)

__global__ __launch_bounds__(NTHR)
void reservoir_kernel(const float* __restrict__ x,
                      const float* __restrict__ init_state,
                      const float* __restrict__ W_in,
                      const float* __restrict__ W,
                      float* __restrict__ out,
                      float* __restrict__ exch,          // [NT][2][NRES]
                      uint32_t* __restrict__ barrier_cnt) // [NT] padded by 64 uints
{
    extern __shared__ char lds[];
    float*    s_state = (float*)lds;                                   // 2048
    float*    s_vals  = (float*)(lds + 8192);                          // 64*RSTR
    float*    s_win   = (float*)(lds + 8192 + 64*RSTR*4);              // 64*WSTR
    float*    s_xt    = (float*)(lds + 8192 + 64*RSTR*4 + 64*WSTR*4);  // 64
    float*    s_pout  = s_xt + 64;                                     // 64
    uint32_t* s_pad   = (uint32_t*)(s_pout + 64);                      // 64
    uint16_t* s_idx   = (uint16_t*)(s_pad + 64);                       // 64*RSTR

    const int tid     = threadIdx.x;
    const int bid     = blockIdx.x;
    const int team    = bid & (NT - 1);     // blockIdx % 8: XCD round-robin heuristic
    const int wgi     = bid >> 3;           // 0..31 within team
    const int rowbase = wgi * RPW;          // global row base owned by this wg

    // ---- initial state (init_state is the true init; any bounded start works for burn-in) ----
    for (int k = tid; k < NRES; k += NTHR) s_state[k] = init_state[k];

    // ---- W_in rows -> LDS (stride WSTR to spread banks) ----
    for (int k = tid; k < RPW * IDIM; k += NTHR) {
        int r = k >> 6, i = k & 63;
        s_win[r * WSTR + i] = W_in[(size_t)(rowbase + r) * IDIM + i];
    }

    // ---- sparse extraction: wave w compacts rows [8w, 8w+8) via ballot ranks ----
    {
        const int wave = tid >> 6, lane = tid & 63;
        const uint64_t below = (lane == 63) ? ~0ull >> 1 : ((1ull << lane) - 1ull);
        for (int rr = 0; rr < 8; ++rr) {
            const int r = wave * 8 + rr;
            const float* wrow = W + (size_t)(rowbase + r) * NRES;
            int cnt = 0;
            for (int c = 0; c < NRES; c += 64) {
                float v = wrow[c + lane];
                bool nz = (v != 0.0f);
                uint64_t m = __ballot(nz);
                int pos = __popcll(m & below);
                if (nz && (cnt + pos) < RCAP) {
                    s_vals[r * RSTR + cnt + pos] = v;
                    s_idx [r * RSTR + cnt + pos] = (uint16_t)(c + lane);
                }
                cnt += __popcll(m);
                if (cnt > RCAP) cnt = RCAP;
            }
            int pad = (cnt + 7) & ~7;
            for (int k = cnt + lane; k < pad; k += 64) {
                s_vals[r * RSTR + k] = 0.0f;
                s_idx [r * RSTR + k] = 0;
            }
            if (lane == 0) s_pad[r] = (uint32_t)pad;
        }
    }

    const int t_start   = (team == 0) ? 0 : team * SEGL - BURN;
    const int nsteps    = (team == 0) ? SEGL : SEGL + BURN;
    const int out_begin = team * SEGL;

    float*    exch_team = exch + (size_t)team * 2 * NRES;
    uint32_t* cntp      = barrier_cnt + team * 64;   // 256B-padded per team

    const int r_my = tid >> 3;   // row handled by this thread (8 threads/row)
    const int j    = tid & 7;

    __syncthreads();

    for (int step = 0; step < nsteps; ++step) {
        const int t = t_start + step;
        if (tid < 64) s_xt[tid] = x[(size_t)t * IDIM + tid];
        __syncthreads();

        // ---- row dot: on-the-fly input projection + sparse W gather ----
        float sum = 0.0f;
        {
            const float* wr = s_win + r_my * WSTR;
            #pragma unroll
            for (int i = j; i < IDIM; i += 8) sum += wr[i] * s_xt[i];
            const int base = r_my * RSTR;
            const int pc = (int)s_pad[r_my];
            for (int k = j; k < pc; k += 8)
                sum += s_vals[base + k] * s_state[s_idx[base + k]];
        }
        sum += __shfl_xor(sum, 1);
        sum += __shfl_xor(sum, 2);
        sum += __shfl_xor(sum, 4);
        if (j == 0) {
            float snew = tanhf(sum);
            float sold = s_state[rowbase + r_my];
            s_pout[r_my] = 0.9f * sold + 0.1f * snew;   // leaky update; output value
        }
        __syncthreads();

        // ---- publish own 64 values (agent-scope, LLC-coherent) + write output ----
        float* gbuf = exch_team + (size_t)(step & 1) * NRES;
        if (tid < 64) {
            float v = s_pout[tid];
            __hip_atomic_store(&gbuf[rowbase + tid], v,
                               __ATOMIC_RELAXED, __HIP_MEMORY_SCOPE_AGENT);
            if (t >= out_begin)
                out[(size_t)t * NRES + rowbase + tid] = v;
        }

        // ---- intra-team barrier: monotonic counter, release/acquire at agent scope.
        // tid0 is in wave0, so the release's s_waitcnt drains wave0's publish stores.
        if (tid == 0) {
            __hip_atomic_fetch_add(cntp, 1u, __ATOMIC_RELEASE, __HIP_MEMORY_SCOPE_AGENT);
            const uint32_t target = (uint32_t)(GW * (step + 1));
            while (__hip_atomic_load(cntp, __ATOMIC_ACQUIRE, __HIP_MEMORY_SCOPE_AGENT) < target) { }
        }
        __syncthreads();

        // ---- refill full state from exchange buffer ----
        #pragma unroll
        for (int q = 0; q < 4; ++q) {
            const int k = tid * 4 + q;
            s_state[k] = __hip_atomic_load(&gbuf[k],
                                           __ATOMIC_RELAXED, __HIP_MEMORY_SCOPE_AGENT);
        }
        __syncthreads();
    }
}

extern "C" void kernel_launch(void* const* d_in, const int* in_sizes, int n_in,
                              void* d_out, int out_size, void* d_ws, size_t ws_size,
                              hipStream_t stream) {
    const float* x          = (const float*)d_in[0];  // [8192, 64]
    const float* init_state = (const float*)d_in[1];  // [2048]
    const float* W_in       = (const float*)d_in[2];  // [2048, 64]
    const float* W          = (const float*)d_in[3];  // [2048, 2048]
    float* out = (float*)d_out;                       // [8192, 2048]

    uint32_t* cnt  = (uint32_t*)d_ws;                 // 8 teams * 64 uints (padded)
    float*    exch = (float*)((char*)d_ws + 4096);    // 8 * 2 * 2048 floats

    // zero the barrier counters (d_ws is poisoned 0xAA before every launch)
    hipMemsetAsync(d_ws, 0, 4096, stream);

    hipFuncSetAttribute((const void*)reservoir_kernel,
                        hipFuncAttributeMaxDynamicSharedMemorySize, LDS_BYTES);

    void* args[] = {(void*)&x, (void*)&init_state, (void*)&W_in, (void*)&W,
                    (void*)&out, (void*)&exch, (void*)&cnt};
    hipLaunchCooperativeKernel((void*)reservoir_kernel,
                               dim3(NT * GW), dim3(NTHR),
                               args, LDS_BYTES, stream);
}

// Round 2
// 6686.834 us; speedup vs baseline: 2.0944x; 2.0944x over previous
//
#include <hip/hip_runtime.h>
#include <cstdint>

#define NT    8      // teams (segments)
#define GW    32     // workgroups per team
#define RPW   64     // rows per workgroup (2048 / 32)
#define NTHR  512    // threads per workgroup
#define NRES  2048
#define IDIM  64
#define TTOT  8192
#define SEGL  1024   // TTOT / NT
#define BURN  512    // burn-in steps (echo-state washout) — R1 measured absmax 3.9e-3, keep
#define RSTR  292    // packed row stride (292%32=4 -> 2-way LDS aliasing = free)
#define RCAP  288    // max nnz kept per row (mean 205, sigma 13.6 -> 6 sigma safe)
#define WSTR  68     // W_in LDS row stride (floats)
#define FLAG_STRIDE 32  // dwords between team-member flags (128 B: own MALL line)

// LDS carve (bytes):
//  s_state : 2048 f       = 8192
//  s_pack  : 64*RSTR u32  = 74752   (idx<<16 | int16 qval)
//  s_win   : 64*WSTR f    = 17408
//  s_xt, s_pout, s_rsc : 64 f each; s_pad : 64 u32   = 1024
#define LDS_BYTES (8192 + 64*RSTR*4 + 64*WSTR*4 + 1024)

typedef float v4f __attribute__((ext_vector_type(4)));

__global__ __launch_bounds__(NTHR)
void reservoir_kernel(const float* __restrict__ x,
                      const float* __restrict__ init_state,
                      const float* __restrict__ W_in,
                      const float* __restrict__ W,
                      float* __restrict__ out,
                      float* __restrict__ exch,     // [NT][2][NRES]
                      uint32_t* __restrict__ flags) // [NT][GW] spaced FLAG_STRIDE dwords
{
    extern __shared__ char lds[];
    float*    s_state = (float*)lds;                              // 2048
    uint32_t* s_pack  = (uint32_t*)(lds + 8192);                  // 64*RSTR
    float*    s_win   = (float*)(lds + 8192 + 64*RSTR*4);         // 64*WSTR
    float*    s_xt    = (float*)(lds + 8192 + 64*RSTR*4 + 64*WSTR*4); // 64
    float*    s_pout  = s_xt + 64;                                // 64
    float*    s_rsc   = s_pout + 64;                              // 64 per-row dequant scale
    uint32_t* s_pad   = (uint32_t*)(s_rsc + 64);                  // 64

    const int tid     = threadIdx.x;
    const int bid     = blockIdx.x;
    const int team    = bid & (NT - 1);   // bid%8: teammates share an XCD (locality only)
    const int wgi     = bid >> 3;         // 0..31 within team
    const int rowbase = wgi * RPW;

    for (int k = tid; k < NRES; k += NTHR) s_state[k] = init_state[k];

    for (int k = tid; k < RPW * IDIM; k += NTHR) {
        int r = k >> 6, i = k & 63;
        s_win[r * WSTR + i] = W_in[(size_t)(rowbase + r) * IDIM + i];
    }

    // ---- sparse extraction + per-row int16 quantization ----
    {
        const int wave = tid >> 6, lane = tid & 63;
        const uint64_t below = (lane == 63) ? ~0ull >> 1 : ((1ull << lane) - 1ull);
        for (int rr = 0; rr < 8; ++rr) {
            const int r = wave * 8 + rr;
            const float* wrow = W + (size_t)(rowbase + r) * NRES;
            // pass 1: row max |v|
            float mx = 0.0f;
            for (int c = lane; c < NRES; c += 64) mx = fmaxf(mx, fabsf(wrow[c]));
            #pragma unroll
            for (int off = 1; off < 64; off <<= 1) mx = fmaxf(mx, __shfl_xor(mx, off));
            const float qs = 32767.0f / fmaxf(mx, 1e-30f);
            // pass 2: ballot-compact + quantize
            int cnt = 0;
            for (int c = 0; c < NRES; c += 64) {
                float v = wrow[c + lane];
                bool nz = (v != 0.0f);
                uint64_t m = __ballot(nz);
                int pos = __popcll(m & below);
                if (nz && (cnt + pos) < RCAP) {
                    int q = (int)rintf(v * qs);
                    q = q > 32767 ? 32767 : (q < -32767 ? -32767 : q);
                    s_pack[r * RSTR + cnt + pos] =
                        ((uint32_t)(c + lane) << 16) | ((uint32_t)q & 0xffffu);
                }
                cnt += __popcll(m);
                if (cnt > RCAP) cnt = RCAP;
            }
            int pad = (cnt + 7) & ~7;
            for (int k = cnt + lane; k < pad; k += 64) s_pack[r * RSTR + k] = 0u;
            if (lane == 0) { s_pad[r] = (uint32_t)pad; s_rsc[r] = mx / 32767.0f; }
        }
    }

    const int t_start   = (team == 0) ? 0 : team * SEGL - BURN;
    const int nsteps    = (team == 0) ? SEGL : SEGL + BURN;
    const int out_begin = team * SEGL;

    float*    exch_team  = exch  + (size_t)team * 2 * NRES;
    uint32_t* flags_team = flags + (size_t)team * GW * FLAG_STRIDE;
    uint32_t* myflag     = flags_team + wgi * FLAG_STRIDE;

    const int r_my = tid >> 3;   // 8 threads per row
    const int j    = tid & 7;

    // prologue: x for first step
    if (tid < 64) s_xt[tid] = x[(size_t)t_start * IDIM + tid];
    __syncthreads();

    for (int step = 0; step < nsteps; ++step) {
        const int t = t_start + step;

        // ---- compute: input proj (f32) + sparse gather (int16 fixed-point) ----
        float sumA = 0.0f, sumQ = 0.0f;
        {
            const float* wr = s_win + r_my * WSTR;
            #pragma unroll
            for (int i = j; i < IDIM; i += 8) sumA += wr[i] * s_xt[i];
            const uint32_t* pk = s_pack + r_my * RSTR;
            const int pc = (int)s_pad[r_my];
            for (int k = j; k < pc; k += 8) {
                uint32_t p = pk[k];
                sumQ += (float)(int)(short)p * s_state[p >> 16];
            }
        }
        float sum = sumA + s_rsc[r_my] * sumQ;
        sum += __shfl_xor(sum, 1);
        sum += __shfl_xor(sum, 2);
        sum += __shfl_xor(sum, 4);
        if (j == 0) {
            float snew = tanhf(sum);
            s_pout[r_my] = 0.9f * s_state[rowbase + r_my] + 0.1f * snew;
        }
        __syncthreads();   // (B) s_pout ready; all done reading s_state/s_xt

        float* gbuf = exch_team + (size_t)(step & 1) * NRES;
        float xpre = 0.0f;
        if (tid < 64) {
            // publish own 64 values (relaxed agent => plain sc1 store, MALL-coherent)
            float v = s_pout[tid];
            __hip_atomic_store(&gbuf[rowbase + tid], v,
                               __ATOMIC_RELAXED, __HIP_MEMORY_SCOPE_AGENT);
            if (t >= out_begin)
                out[(size_t)t * NRES + rowbase + tid] = v;

            // prefetch next x during the wait window
            int tn = t + 1; if (tn >= TTOT) tn = TTOT - 1;
            xpre = x[(size_t)tn * IDIM + tid];

            if (tid == 0) {
                // release without buffer_wbl2: drain wave-0's sc1 publish stores,
                // then set flag. ("memory" pins ordering against the optimizer.)
                asm volatile("s_waitcnt vmcnt(0)" ::: "memory");
                __hip_atomic_store(myflag, (uint32_t)(step + 1),
                                   __ATOMIC_RELAXED, __HIP_MEMORY_SCOPE_AGENT);
            }

            // parallel poll: lane l (<GW) watches teammate l's flag; no buffer_inv.
            const uint32_t target = (uint32_t)(step + 1);
            uint32_t* fl = flags_team + (tid & (GW - 1)) * FLAG_STRIDE;
            const bool watcher = (tid < GW);
            while (true) {
                uint32_t v = watcher
                    ? __hip_atomic_load(fl, __ATOMIC_RELAXED, __HIP_MEMORY_SCOPE_AGENT)
                    : target;
                if (__ballot(v >= target) == ~0ull) break;
            }
            s_xt[tid] = xpre;   // safe: all readers passed barrier (B)
        }
        __syncthreads();   // (C) barrier done for whole block

        // ---- refill full state: dwordx4 sc1 loads from MALL ----
        {
            v4f sv;
            const float* gp = gbuf + tid * 4;
            asm volatile("global_load_dwordx4 %0, %1, off sc1\n\t"
                         "s_waitcnt vmcnt(0)"
                         : "=v"(sv) : "v"(gp) : "memory");
            *(v4f*)(s_state + tid * 4) = sv;
        }
        __syncthreads();   // (A) s_state/s_xt ready for next step
    }
}

extern "C" void kernel_launch(void* const* d_in, const int* in_sizes, int n_in,
                              void* d_out, int out_size, void* d_ws, size_t ws_size,
                              hipStream_t stream) {
    const float* x          = (const float*)d_in[0];  // [8192, 64]
    const float* init_state = (const float*)d_in[1];  // [2048]
    const float* W_in       = (const float*)d_in[2];  // [2048, 64]
    const float* W          = (const float*)d_in[3];  // [2048, 2048]
    float* out = (float*)d_out;                       // [8192, 2048]

    uint32_t* flags = (uint32_t*)d_ws;                 // 8*32 flags, 128 B apart = 32 KB
    float*    exch  = (float*)((char*)d_ws + 32768);   // 8*2*2048 floats

    hipMemsetAsync(d_ws, 0, 32768, stream);  // flags start at 0 (ws is re-poisoned 0xAA)

    hipFuncSetAttribute((const void*)reservoir_kernel,
                        hipFuncAttributeMaxDynamicSharedMemorySize, LDS_BYTES);

    void* args[] = {(void*)&x, (void*)&init_state, (void*)&W_in, (void*)&W,
                    (void*)&out, (void*)&exch, (void*)&flags};
    hipLaunchCooperativeKernel((void*)reservoir_kernel,
                               dim3(NT * GW), dim3(NTHR),
                               args, LDS_BYTES, stream);
}

// Round 4
// 3731.818 us; speedup vs baseline: 3.7528x; 1.7918x over previous
//
#include <hip/hip_runtime.h>
#include <cstdint>

#define NT    16     // teams (segments)
#define GW    16     // workgroups per team
#define RPW   128    // rows per workgroup (2048 / 16)
#define NTHR  512
#define NRES  2048
#define IDIM  64
#define TTOT  8192
#define SEGL  512    // TTOT / NT
#define BURN  256    // 0.955^256 * ||s|| ~ 4e-6 — invisible vs 3.9e-3 quant floor
#define POOL  28672  // packed-entry pool per WG (mean ~27.2K, +9 sigma)
#define WSTR  65     // W_in LDS row stride (floats, odd -> bank spread)
#define FS    32     // flag stride in dwords (128 B apart, one MALL line each)

// LDS carve (bytes)
#define OFF_POOL  8192
#define OFF_WIN   (OFF_POOL + POOL*4)        // 122880
#define OFF_XT    (OFF_WIN + RPW*WSTR*4)     // 156160
#define OFF_POUT  (OFF_XT + 256)             // 156416
#define OFF_RSC   (OFF_POUT + 512)           // 156928
#define OFF_CNT   (OFF_RSC + 512)            // 157440
#define OFF_OFFS  (OFF_CNT + 512)            // 157952
#define LDS_BYTES (OFF_OFFS + 512)           // 158464 < 160 KiB

typedef float v4f __attribute__((ext_vector_type(4)));

__global__ __launch_bounds__(NTHR)
void reservoir_kernel(const float* __restrict__ x,
                      const float* __restrict__ init_state,
                      const float* __restrict__ W_in,
                      const float* __restrict__ W,
                      float* __restrict__ out,
                      float* __restrict__ exch,     // [NT][2][NRES]
                      uint32_t* __restrict__ flags) // [NT][GW] spaced FS dwords
{
    extern __shared__ char lds[];
    float*    s_state = (float*)lds;
    uint32_t* s_pool  = (uint32_t*)(lds + OFF_POOL);
    float*    s_win   = (float*)(lds + OFF_WIN);
    float*    s_xt    = (float*)(lds + OFF_XT);
    float*    s_pout  = (float*)(lds + OFF_POUT);
    float*    s_rsc   = (float*)(lds + OFF_RSC);
    uint32_t* s_cnt   = (uint32_t*)(lds + OFF_CNT);
    uint32_t* s_off   = (uint32_t*)(lds + OFF_OFFS);

    const int tid = threadIdx.x;
    const int bid = blockIdx.x;
    const int team    = bid & (NT - 1);   // teams interleaved across XCDs (locality only)
    const int wgi     = bid >> 4;         // 0..15 within team
    const int rowbase = wgi * RPW;

    for (int k = tid; k < NRES; k += NTHR) s_state[k] = init_state[k];
    for (int k = tid; k < RPW * IDIM; k += NTHR) {
        int r = k >> 6, i = k & 63;
        s_win[r * WSTR + i] = W_in[(size_t)(rowbase + r) * IDIM + i];
    }

    const int wave = tid >> 6, lane = tid & 63;

    // ---- pass A: per-row nnz count + max|v| ----
    for (int rr = 0; rr < 16; ++rr) {
        const int r = wave * 16 + rr;
        const float* wrow = W + (size_t)(rowbase + r) * NRES;
        float mx = 0.0f; int cnt = 0;
        for (int c = lane; c < NRES; c += 64) {
            float v = wrow[c];
            mx = fmaxf(mx, fabsf(v));
            cnt += (v != 0.0f) ? 1 : 0;
        }
        #pragma unroll
        for (int o = 1; o < 64; o <<= 1) {
            mx = fmaxf(mx, __shfl_xor(mx, o));
            cnt += __shfl_xor(cnt, o);
        }
        if (lane == 0) { s_cnt[r] = (uint32_t)cnt; s_rsc[r] = mx; }
    }
    __syncthreads();
    // ---- prefix sum of pad16 counts (serial, init-only) ----
    if (tid == 0) {
        uint32_t acc = 0;
        for (int r2 = 0; r2 < RPW; ++r2) {
            uint32_t c = s_cnt[r2];
            uint32_t pad = (c + 15u) & ~15u;
            if (acc + pad > POOL) pad = (POOL > acc) ? ((POOL - acc) & ~15u) : 0u;
            s_off[r2] = acc;
            s_cnt[r2] = pad;      // repurposed: padded count
            acc += pad;
        }
    }
    __syncthreads();
    // ---- pass B: ballot-compact + int16 quantize into CSR pool ----
    for (int rr = 0; rr < 16; ++rr) {
        const int r = wave * 16 + rr;
        const float* wrow = W + (size_t)(rowbase + r) * NRES;
        const uint32_t off = s_off[r];
        const uint32_t pad = s_cnt[r];
        const float mx = s_rsc[r];
        const float qs = 32767.0f / fmaxf(mx, 1e-30f);
        const uint64_t below = (lane == 63) ? (~0ull >> 1) : ((1ull << lane) - 1ull);
        uint32_t cnt = 0;
        for (int c = 0; c < NRES; c += 64) {
            float v = wrow[c + lane];
            bool nz = (v != 0.0f);
            uint64_t m = __ballot(nz);
            uint32_t pos = (uint32_t)__popcll(m & below);
            if (nz && (cnt + pos) < pad) {
                int q = (int)rintf(v * qs);
                q = q > 32767 ? 32767 : (q < -32767 ? -32767 : q);
                s_pool[off + cnt + pos] =
                    ((uint32_t)(c + lane) << 16) | ((uint32_t)q & 0xffffu);
            }
            cnt += (uint32_t)__popcll(m);
            if (cnt > pad) cnt = pad;
        }
        for (uint32_t k = cnt + lane; k < pad; k += 64) s_pool[off + k] = 0u;
        if (lane == 0) { s_cnt[r] = pad >> 4; s_rsc[r] = mx * (1.0f / 32767.0f); }
    }
    __syncthreads();

    const int t_start   = (team == 0) ? 0 : team * SEGL - BURN;
    const int nsteps    = (team == 0) ? SEGL : SEGL + BURN;
    const int out_begin = team * SEGL;

    float*    exch_team  = exch  + (size_t)team * 2 * NRES;
    uint32_t* flags_team = flags + (size_t)team * GW * FS;
    uint32_t* myflag     = flags_team + wgi * FS;

    const int r_my = tid >> 2;             // 4 threads per row
    const int j    = tid & 3;
    const uint32_t off_my = s_off[r_my];
    const int      nq_my  = (int)s_cnt[r_my];          // uint4 iterations per thread
    const float    rsc_my = s_rsc[r_my];
    const uint4*   pk_my  = (const uint4*)(s_pool + off_my) + (size_t)j * nq_my;
    const float*   win_my = s_win + r_my * WSTR;

    if (tid < 64) s_xt[tid] = x[(size_t)t_start * IDIM + tid];
    __syncthreads();

    for (int step = 0; step < nsteps; ++step) {
        const int t = t_start + step;

        // ---- compute: input proj (f32) + CSR gather (int16 fixed-point) ----
        float sumA = 0.0f, sumQ = 0.0f;
        #pragma unroll
        for (int i = j; i < IDIM; i += 4) sumA += win_my[i] * s_xt[i];
        for (int k = 0; k < nq_my; ++k) {
            uint4 p = pk_my[k];   // ds_read_b128: 4 packed nnz
            sumQ += (float)(short)(p.x & 0xffffu) * s_state[p.x >> 16];
            sumQ += (float)(short)(p.y & 0xffffu) * s_state[p.y >> 16];
            sumQ += (float)(short)(p.z & 0xffffu) * s_state[p.z >> 16];
            sumQ += (float)(short)(p.w & 0xffffu) * s_state[p.w >> 16];
        }
        float sum = sumA + rsc_my * sumQ;
        sum += __shfl_xor(sum, 1);
        sum += __shfl_xor(sum, 2);
        if (j == 0)
            s_pout[r_my] = 0.9f * s_state[rowbase + r_my] + 0.1f * tanhf(sum);
        __syncthreads();   // (B) s_pout ready; all waves done with s_state/s_xt

        float* gbuf = exch_team + (size_t)(step & 1) * NRES;
        if (tid < 64) {
            // wave 0 publishes all 128 values (sc1 -> MALL-coherent), then one
            // per-wave vmcnt drain, then lane0 posts the flag (release).
            float v0 = s_pout[tid], v1 = s_pout[tid + 64];
            asm volatile("global_store_dword %0, %1, off sc1" :: "v"(&gbuf[rowbase + tid]), "v"(v0) : "memory");
            asm volatile("global_store_dword %0, %1, off sc1" :: "v"(&gbuf[rowbase + 64 + tid]), "v"(v1) : "memory");
            asm volatile("s_waitcnt vmcnt(0)" ::: "memory");
            if (tid == 0)
                asm volatile("global_store_dword %0, %1, off sc1" :: "v"(myflag), "v"((uint32_t)(step + 1)) : "memory");

            // off-critical-path work inside the wait window
            if (t >= out_begin) {
                out[(size_t)t * NRES + rowbase + tid]      = v0;
                out[(size_t)t * NRES + rowbase + 64 + tid] = v1;
            }
            int tn = t + 1; if (tn >= TTOT) tn = TTOT - 1;
            float xpre = x[(size_t)tn * IDIM + tid];

            // poll: lane watches flag (tid & 15); 4 lanes per flag
            const uint32_t target = (uint32_t)(step + 1);
            uint32_t* fl = flags_team + (tid & 15) * FS;
            while (true) {
                uint32_t v;
                asm volatile("global_load_dword %0, %1, off sc1\n\ts_waitcnt vmcnt(0)"
                             : "=v"(v) : "v"(fl) : "memory");
                if (__ballot(v >= target) == ~0ull) break;
            }
            s_xt[tid] = xpre;   // safe: all readers passed barrier (B)
        }
        __syncthreads();   // (C) team barrier complete for whole block

        // ---- refill full state from exchange buffer ----
        {
            v4f sv;
            const float* gp = gbuf + tid * 4;
            asm volatile("global_load_dwordx4 %0, %1, off sc1\n\ts_waitcnt vmcnt(0)"
                         : "=v"(sv) : "v"(gp) : "memory");
            *(v4f*)(s_state + tid * 4) = sv;
        }
        __syncthreads();   // (A) s_state/s_xt ready for next step
    }
}

extern "C" void kernel_launch(void* const* d_in, const int* in_sizes, int n_in,
                              void* d_out, int out_size, void* d_ws, size_t ws_size,
                              hipStream_t stream) {
    const float* x          = (const float*)d_in[0];  // [8192, 64]
    const float* init_state = (const float*)d_in[1];  // [2048]
    const float* W_in       = (const float*)d_in[2];  // [2048, 64]
    const float* W          = (const float*)d_in[3];  // [2048, 2048]
    float* out = (float*)d_out;                       // [8192, 2048]

    uint32_t* flags = (uint32_t*)d_ws;                 // 16*16 flags @128B = 32 KB
    float*    exch  = (float*)((char*)d_ws + 32768);   // 16*2*2048 floats = 256 KB

    hipMemsetAsync(d_ws, 0, 32768, stream);  // zero flags (ws re-poisoned 0xAA each launch)

    hipFuncSetAttribute((const void*)reservoir_kernel,
                        hipFuncAttributeMaxDynamicSharedMemorySize, LDS_BYTES);

    void* args[] = {(void*)&x, (void*)&init_state, (void*)&W_in, (void*)&W,
                    (void*)&out, (void*)&exch, (void*)&flags};
    hipLaunchCooperativeKernel((void*)reservoir_kernel,
                               dim3(NT * GW), dim3(NTHR),
                               args, LDS_BYTES, stream);
}

// Round 5
// 3678.853 us; speedup vs baseline: 3.8068x; 1.0144x over previous
//
#include <hip/hip_runtime.h>
#include <cstdint>

#define NT    16     // teams (segments)
#define GW    16     // workgroups per team
#define RPW   128    // rows per workgroup
#define NTHR  512
#define NRES  2048
#define IDIM  64
#define TTOT  8192
#define SEGL  512    // TTOT / NT
#define BURN  256    // proven R4: absmax 3.9e-3
#define POOL  30720  // packed-entry pool (mean ~27.3K, ~20 sigma margin)

// LDS offsets (bytes)
#define OFF_POOL  8192
#define OFF_WINQ  (OFF_POOL + POOL*4)   // 131072 (16KB; bucketex scratch during init)
#define OFF_XT    (OFF_WINQ + 16384)    // 147456
#define OFF_POUT  (OFF_XT + 256)        // 147712
#define OFF_RSC   (OFF_POUT + 512)      // 148224
#define OFF_RSC2  (OFF_RSC + 512)       // 148736
#define OFF_OFF2  (OFF_RSC2 + 512)      // 149248  [512] segment base (dwords)
#define OFF_NQ    (OFF_OFF2 + 2048)     // 151296  [512] segment uint4 count
#define OFF_SEGC  (OFF_NQ + 2048)       // 153344  [512] segment entry count
#define LDS_BYTES (OFF_SEGC + 2048)     // 155392 < 163840

typedef float    v4f __attribute__((ext_vector_type(4)));
typedef uint32_t v2u __attribute__((ext_vector_type(2)));
typedef uint32_t v4u __attribute__((ext_vector_type(4)));

__global__ __launch_bounds__(NTHR)
void reservoir_kernel(const float* __restrict__ x,
                      const float* __restrict__ init_state,
                      const float* __restrict__ W_in,
                      const float* __restrict__ W,
                      float* __restrict__ out,
                      uint32_t* __restrict__ exch)  // [NT][2][2048] (val,tag) pairs
{
    extern __shared__ char lds[];
    float*    s_state = (float*)lds;
    uint32_t* s_pool  = (uint32_t*)(lds + OFF_POOL);
    uint16_t* s_winq  = (uint16_t*)(lds + OFF_WINQ);
    uint32_t* s_bex   = (uint32_t*)(lds + OFF_WINQ);   // init-time alias: [128][32]
    float*    s_xt    = (float*)(lds + OFF_XT);
    float*    s_pout  = (float*)(lds + OFF_POUT);
    float*    s_rsc   = (float*)(lds + OFF_RSC);
    float*    s_rsc2  = (float*)(lds + OFF_RSC2);
    uint32_t* s_off2  = (uint32_t*)(lds + OFF_OFF2);
    uint32_t* s_nq    = (uint32_t*)(lds + OFF_NQ);
    uint32_t* s_segc  = (uint32_t*)(lds + OFF_SEGC);

    const int tid = threadIdx.x;
    const int bid = blockIdx.x;
    const int team    = bid & (NT - 1);
    const int wgi     = bid >> 4;
    const int rowbase = wgi * RPW;

    for (int k = tid; k < NRES; k += NTHR) s_state[k] = init_state[k];

    const int wave = tid >> 6, lane = tid & 63;
    const int bnk  = lane & 31;

    // ---- pass A: per-(row,bank) counts + row max|v|; octet scan ----
    for (int rr = 0; rr < 16; ++rr) {
        const int r = wave * 16 + rr;
        const float* wrow = W + (size_t)(rowbase + r) * NRES;
        float mx = 0.0f; int cntb = 0;
        for (int c = 0; c < NRES; c += 64) {
            float v = wrow[c + lane];
            mx = fmaxf(mx, fabsf(v));
            uint64_t m = __ballot(v != 0.0f);
            cntb += (int)((m >> bnk) & 1ull) + (int)((m >> (bnk + 32)) & 1ull);
        }
        #pragma unroll
        for (int o = 1; o < 64; o <<= 1) mx = fmaxf(mx, __shfl_xor(mx, o));
        // inclusive scan of cntb within 8-lane (octet) groups
        int incl = cntb;
        #pragma unroll
        for (int d = 1; d < 8; d <<= 1) {
            int t2 = __shfl_up(incl, d, 8);
            if ((lane & 7) >= d) incl += t2;
        }
        int ex  = incl - cntb;                 // exclusive within-octet prefix
        int tot = __shfl(incl, 7, 8);          // octet total
        if (lane < 32) s_bex[r * 32 + lane] = (uint32_t)ex;
        if (lane < 32 && (lane & 7) == 0) s_segc[r * 4 + (lane >> 3)] = (uint32_t)tot;
        if (lane == 0) s_rsc[r] = mx;          // raw max for now
    }
    __syncthreads();

    // ---- prefix over 512 segments (one wave), pad4, clamp ----
    if (tid < 64) {
        uint32_t csz[8]; uint32_t loc = 0;
        for (int i = 0; i < 8; ++i) {
            uint32_t c = s_segc[tid * 8 + i];
            uint32_t p = (c + 3u) & ~3u;
            csz[i] = p; loc += p;
        }
        int incl = (int)loc;
        #pragma unroll
        for (int d = 1; d < 64; d <<= 1) {
            int t2 = __shfl_up(incl, d);
            if (tid >= d) incl += t2;
        }
        uint32_t base = (uint32_t)incl - loc;
        for (int i = 0; i < 8; ++i) {
            int seg = tid * 8 + i;
            uint32_t b = base, p = csz[i], c = s_segc[seg];
            if (b > POOL) b = POOL;
            if (b + p > POOL) p = (POOL - b) & ~3u;
            if (c > p) c = p;
            s_off2[seg] = b; s_nq[seg] = p >> 2; s_segc[seg] = c;
            base += csz[i];
        }
    }
    __syncthreads();

    // ---- pass B: ballot-rank scatter into bank-bucketed CSR + int16 quantize ----
    for (int rr = 0; rr < 16; ++rr) {
        const int r = wave * 16 + rr;
        const float* wrow = W + (size_t)(rowbase + r) * NRES;
        const float mx = s_rsc[r];
        const float qs = 32767.0f / fmaxf(mx, 1e-30f);
        int cur = (int)s_off2[r * 4 + (bnk >> 3)] + (int)s_bex[r * 32 + bnk];
        for (int c = 0; c < NRES; c += 64) {
            float v = wrow[c + lane];
            bool nz = (v != 0.0f);
            uint64_t m = __ballot(nz);
            int rank = (lane >= 32) ? (int)((m >> (lane - 32)) & 1ull) : 0;
            int curB = __shfl(cur, bnk);
            if (nz) {
                int q = (int)rintf(v * qs);
                q = q > 32767 ? 32767 : (q < -32767 ? -32767 : q);
                int dest = curB + rank;
                if (dest < POOL)
                    s_pool[dest] = ((uint32_t)(c + lane) << 16) | ((uint32_t)q & 0xffffu);
            }
            cur += (int)((m >> bnk) & 1ull) + (int)((m >> (bnk + 32)) & 1ull);
        }
    }
    __syncthreads();

    // ---- zero-pad segments; finalize W scale; quantize W_in (overwrites s_bex) ----
    {
        uint32_t b = s_off2[tid], c = s_segc[tid], p = s_nq[tid] << 2;
        for (uint32_t k = c; k < p; ++k) s_pool[b + k] = 0u;
        if (tid < 128) s_rsc[tid] *= (1.0f / 32767.0f);
    }
    __syncthreads();
    {
        const int r = tid >> 2, j = tid & 3;
        const float* wirow = W_in + (size_t)(rowbase + r) * IDIM + 16 * j;
        float w16[16]; float mxw = 0.0f;
        #pragma unroll
        for (int k = 0; k < 16; ++k) { w16[k] = wirow[k]; mxw = fmaxf(mxw, fabsf(w16[k])); }
        mxw = fmaxf(mxw, __shfl_xor(mxw, 1));
        mxw = fmaxf(mxw, __shfl_xor(mxw, 2));
        const float qs2 = 32767.0f / fmaxf(mxw, 1e-30f);
        if (j == 0) s_rsc2[r] = mxw * (1.0f / 32767.0f);
        uint16_t* wq = s_winq + tid * 16;
        #pragma unroll
        for (int k = 0; k < 16; ++k) {
            int q = (int)rintf(w16[k] * qs2);
            q = q > 32767 ? 32767 : (q < -32767 ? -32767 : q);
            wq[k] = (uint16_t)(q & 0xffff);
        }
    }
    __syncthreads();

    // ---- per-thread runtime constants ----
    const int r_my = tid >> 2;
    const int j    = tid & 3;
    const uint32_t base_my = s_off2[tid];
    const int      nq_my   = (int)s_nq[tid];
    const int      rot_my  = ((r_my & 7) * nq_my) >> 3;   // bank-phase stagger
    const float    rsc_my  = s_rsc[r_my];
    const float    rsc2_my = s_rsc2[r_my];
    const uint4*   pool4   = (const uint4*)(s_pool + base_my);
    const uint4*   wqv     = (const uint4*)(s_winq + tid * 16);
    const uint4    wa0 = wqv[0], wa1 = wqv[1];            // W_in slice, resident

    const int t_start   = (team == 0) ? 0 : team * SEGL - BURN;
    const int nsteps    = (team == 0) ? SEGL : SEGL + BURN;
    const int out_begin = team * SEGL;
    uint32_t* exch_team = exch + (size_t)team * 2 * 4096;

    if (tid < 64) s_xt[tid] = x[(size_t)t_start * IDIM + tid];
    __syncthreads();

    for (int step = 0; step < nsteps; ++step) {
        const int t = t_start + step;
        const uint32_t tag = (uint32_t)(step + 1);

        // ---- input proj: int16 W_in (2 b128) x f32 xt (4 b128), contiguous slice ----
        float sumP = 0.0f, sumQ = 0.0f;
        {
            const v4f* xv = (const v4f*)(s_xt + 16 * j);
            v4f x0 = xv[0], x1 = xv[1], x2 = xv[2], x3 = xv[3];
            #define LO(w) ((float)((int)((w) << 16) >> 16))
            #define HI(w) ((float)((int)(w) >> 16))
            sumP += LO(wa0.x)*x0.x + HI(wa0.x)*x0.y + LO(wa0.y)*x0.z + HI(wa0.y)*x0.w;
            sumP += LO(wa0.z)*x1.x + HI(wa0.z)*x1.y + LO(wa0.w)*x1.z + HI(wa0.w)*x1.w;
            sumP += LO(wa1.x)*x2.x + HI(wa1.x)*x2.y + LO(wa1.y)*x2.z + HI(wa1.y)*x2.w;
            sumP += LO(wa1.z)*x3.x + HI(wa1.z)*x3.y + LO(wa1.w)*x3.z + HI(wa1.w)*x3.w;
            #undef LO
            #undef HI
        }
        // ---- sparse gather, bank-staggered start ----
        for (int k = 0; k < nq_my; ++k) {
            int kk = k + rot_my; if (kk >= nq_my) kk -= nq_my;
            uint4 p = pool4[kk];
            sumQ += (float)((int)(p.x << 16) >> 16) * s_state[p.x >> 16];
            sumQ += (float)((int)(p.y << 16) >> 16) * s_state[p.y >> 16];
            sumQ += (float)((int)(p.z << 16) >> 16) * s_state[p.z >> 16];
            sumQ += (float)((int)(p.w << 16) >> 16) * s_state[p.w >> 16];
        }
        float sum = rsc2_my * sumP + rsc_my * sumQ;
        sum += __shfl_xor(sum, 1);
        sum += __shfl_xor(sum, 2);
        if (j == 0)
            s_pout[r_my] = 0.9f * s_state[rowbase + r_my] + 0.1f * tanhf(sum);
        __syncthreads();   // (B) s_pout ready; all reads of s_state/s_xt done

        uint32_t* pb = exch_team + (size_t)(step & 1) * 4096;
        if (tid < 64) {
            float v0 = s_pout[tid], v1 = s_pout[tid + 64];
            // tag travels WITH data in one atomic 8B store -> no release drain needed
            v2u pr0; pr0.x = __float_as_uint(v0); pr0.y = tag;
            v2u pr1; pr1.x = __float_as_uint(v1); pr1.y = tag;
            uint32_t* d0 = pb + (size_t)(rowbase + tid) * 2;
            uint32_t* d1 = pb + (size_t)(rowbase + 64 + tid) * 2;
            asm volatile("global_store_dwordx2 %0, %1, off sc1" :: "v"(d0), "v"(pr0) : "memory");
            asm volatile("global_store_dwordx2 %0, %1, off sc1" :: "v"(d1), "v"(pr1) : "memory");
            if (t >= out_begin) {
                out[(size_t)t * NRES + rowbase + tid]      = v0;
                out[(size_t)t * NRES + rowbase + 64 + tid] = v1;
            }
            int tn = t + 1; if (tn >= TTOT) tn = TTOT - 1;
            s_xt[tid] = x[(size_t)tn * IDIM + tid];   // safe: readers passed (B)
        }

        // ---- poll + refill fused: spin on own 4 (val,tag) pairs ----
        {
            uint32_t* p0 = pb + (size_t)tid * 8;
            uint32_t* p1 = p0 + 4;
            v4u A, B2;
            while (true) {
                asm volatile("global_load_dwordx4 %0, %2, off sc1\n\t"
                             "global_load_dwordx4 %1, %3, off sc1\n\t"
                             "s_waitcnt vmcnt(0)"
                             : "=&v"(A), "=&v"(B2)
                             : "v"(p0), "v"(p1)
                             : "memory");
                if (A.y == tag && A.w == tag && B2.y == tag && B2.w == tag) break;
            }
            s_state[tid * 4 + 0] = __uint_as_float(A.x);
            s_state[tid * 4 + 1] = __uint_as_float(A.z);
            s_state[tid * 4 + 2] = __uint_as_float(B2.x);
            s_state[tid * 4 + 3] = __uint_as_float(B2.z);
        }
        __syncthreads();   // (A) s_state/s_xt ready for next step
    }
}

extern "C" void kernel_launch(void* const* d_in, const int* in_sizes, int n_in,
                              void* d_out, int out_size, void* d_ws, size_t ws_size,
                              hipStream_t stream) {
    const float* x          = (const float*)d_in[0];  // [8192, 64]
    const float* init_state = (const float*)d_in[1];  // [2048]
    const float* W_in       = (const float*)d_in[2];  // [2048, 64]
    const float* W          = (const float*)d_in[3];  // [2048, 2048]
    float* out = (float*)d_out;                       // [8192, 2048]

    uint32_t* exch = (uint32_t*)d_ws;   // 16 teams * 2 parity * 2048 pairs * 8B = 512 KB

    // stale tags must differ from 1..768: zero them (0xAA poison would also differ)
    hipMemsetAsync(d_ws, 0, NT * 2 * 4096 * sizeof(uint32_t), stream);

    hipFuncSetAttribute((const void*)reservoir_kernel,
                        hipFuncAttributeMaxDynamicSharedMemorySize, LDS_BYTES);

    void* args[] = {(void*)&x, (void*)&init_state, (void*)&W_in, (void*)&W,
                    (void*)&out, (void*)&exch};
    hipLaunchCooperativeKernel((void*)reservoir_kernel,
                               dim3(NT * GW), dim3(NTHR),
                               args, LDS_BYTES, stream);
}